// Round 2
// baseline (286.993 us; speedup 1.0000x reference)
//
#include <hip/hip_runtime.h>
#include <hip/hip_bf16.h>

#define NUSER 1000
#define NNODES 3000
#define NREL 5
#define HID 500
#define DOUT 75
#define NBASIS 2
#define NEDGES 200000
#define NITEM (NNODES - NUSER)   // 2000
#define NH (NNODES * HID)        // 1,500,000

// ---------------- 1. weight = cumsum(ord_basis, axis=0), float4-vectorized ----
__global__ void k_cumsum(const float4* __restrict__ basis, float4* __restrict__ weight) {
    int i = blockIdx.x * blockDim.x + threadIdx.x;   // over NH/4 = 375000
    if (i >= NH / 4) return;
    float4 s = make_float4(0.f, 0.f, 0.f, 0.f);
#pragma unroll
    for (int r = 0; r < NREL; ++r) {
        float4 b = basis[r * (NH / 4) + i];
        s.x += b.x; s.y += b.y; s.z += b.z; s.w += b.w;
        weight[r * (NH / 4) + i] = s;
    }
}

// ---------------- 2. CSR build: degree, scan, fill ---------------------------
__global__ void k_degree(const int* __restrict__ dst, int* __restrict__ deg) {
    int e = blockIdx.x * blockDim.x + threadIdx.x;
    if (e < NEDGES) atomicAdd(&deg[dst[e]], 1);
}

__global__ void k_scan(const int* __restrict__ deg, int* __restrict__ offs,
                       int* __restrict__ cursor) {
    __shared__ int tmp[1024];
    int t = threadIdx.x;
    int base = t * 3;
    int a = (base     < NNODES) ? deg[base]     : 0;
    int b = (base + 1 < NNODES) ? deg[base + 1] : 0;
    int c = (base + 2 < NNODES) ? deg[base + 2] : 0;
    int s = a + b + c;
    tmp[t] = s;
    __syncthreads();
    for (int d = 1; d < 1024; d <<= 1) {
        int x = (t >= d) ? tmp[t - d] : 0;
        __syncthreads();
        tmp[t] += x;
        __syncthreads();
    }
    int excl = tmp[t] - s;
    if (base < NNODES)     { offs[base]     = excl;         cursor[base]     = excl; }
    if (base + 1 < NNODES) { offs[base + 1] = excl + a;     cursor[base + 1] = excl + a; }
    if (base + 2 < NNODES) { offs[base + 2] = excl + a + b; cursor[base + 2] = excl + a + b; }
    if (t == 1023) offs[NNODES] = tmp[1023];
}

__global__ void k_fill(const int* __restrict__ src, const int* __restrict__ dst,
                       const int* __restrict__ etype, const float* __restrict__ enorm,
                       const int* __restrict__ x,
                       int* __restrict__ cursor, int* __restrict__ csr_row,
                       float* __restrict__ csr_norm) {
    int e = blockIdx.x * blockDim.x + threadIdx.x;
    if (e >= NEDGES) return;
    int d = dst[e];
    int pos = atomicAdd(&cursor[d], 1);
    csr_row[pos] = etype[e] * NNODES + x[src[e]];
    csr_norm[pos] = enorm[e];
}

// ---------------- 3. aggregation + relu: feat[n,h] -------------------------
// one block per node; 256 threads cover 500 cols (t and t+256)
__global__ __launch_bounds__(256) void k_agg(const float* __restrict__ weight,
                                             const int* __restrict__ offs,
                                             const int* __restrict__ csr_row,
                                             const float* __restrict__ csr_norm,
                                             float* __restrict__ feat) {
    int n = blockIdx.x;
    int t = threadIdx.x;
    int beg = offs[n], end = offs[n + 1];
    int c1 = t + 256;
    float acc0 = 0.f, acc1 = 0.f;
    for (int p = beg; p < end; ++p) {
        int row = csr_row[p];         // uniform across block
        float w = csr_norm[p];        // uniform across block
        const float* wr = weight + (size_t)row * HID;
        acc0 += wr[t] * w;
        if (c1 < HID) acc1 += wr[c1] * w;
    }
    feat[(size_t)n * HID + t] = fmaxf(acc0, 0.f);
    if (c1 < HID) feat[(size_t)n * HID + c1] = fmaxf(acc1, 0.f);
}

// ---------------- 4. dense: uv = relu(feat @ W), 4 nodes/block ---------------
#define DN 4
__global__ __launch_bounds__(128) void k_dense(const float* __restrict__ feat,
                                               const float* __restrict__ W,
                                               float* __restrict__ uv) {
    __shared__ float lds[DN][HID];
    int nb = blockIdx.x * DN;
    int t = threadIdx.x;
    for (int j = t; j < DN * HID; j += 128) {
        int nn = j / HID, d = j % HID;
        lds[nn][d] = (nb + nn < NNODES) ? feat[(size_t)(nb + nn) * HID + d] : 0.f;
    }
    __syncthreads();
    if (t < DOUT) {
        float a0 = 0.f, a1 = 0.f, a2 = 0.f, a3 = 0.f;
        for (int d = 0; d < HID; ++d) {
            float w = W[d * DOUT + t];
            a0 += lds[0][d] * w;
            a1 += lds[1][d] * w;
            a2 += lds[2][d] * w;
            a3 += lds[3][d] * w;
        }
        if (nb + 0 < NNODES) uv[(nb + 0) * DOUT + t] = fmaxf(a0, 0.f);
        if (nb + 1 < NNODES) uv[(nb + 1) * DOUT + t] = fmaxf(a1, 0.f);
        if (nb + 2 < NNODES) uv[(nb + 2) * DOUT + t] = fmaxf(a2, 0.f);
        if (nb + 3 < NNODES) uv[(nb + 3) * DOUT + t] = fmaxf(a3, 0.f);
    }
}

// ---------------- 5. T[b,u,e] = sum_d uv[u,d] * bm[b,d,e]  (users only) ------
__global__ void k_T(const float* __restrict__ uv, const float* __restrict__ bm,
                    float* __restrict__ T) {
    int i = blockIdx.x * blockDim.x + threadIdx.x;   // over 2*1000*75
    if (i >= NBASIS * NUSER * DOUT) return;
    int b = i / (NUSER * DOUT);
    int rem = i % (NUSER * DOUT);
    int u = rem / DOUT;
    int e = rem % DOUT;
    float acc = 0.f;
    for (int d = 0; d < DOUT; ++d)
        acc += uv[u * DOUT + d] * bm[b * DOUT * DOUT + d * DOUT + e];
    T[i] = acc;
}

// ---------------- 6. decoder: out[u,i,r] = sum_b coefs[r,b] * T_b[u,:].item[i,:]
// tile 32u x 128i, e-chunks of 25; per thread 2u x 8i x 2b = 32 acc
#define UT 32
#define IT 128
#define EC 25
__global__ __launch_bounds__(256) void k_dec(const float* __restrict__ T,
                                             const float* __restrict__ uv,
                                             const float* __restrict__ coefs,
                                             float* __restrict__ out) {
    __shared__ float As[NBASIS][UT][EC];
    __shared__ float Is[IT][EC];
    int t = threadIdx.x;
    int ti = t & 15, tu = t >> 4;     // 16 x 16
    int ub = blockIdx.y * UT;
    int ib = blockIdx.x * IT;

    float acc[NBASIS][2][8];
#pragma unroll
    for (int b = 0; b < NBASIS; ++b)
#pragma unroll
        for (int uu = 0; uu < 2; ++uu)
#pragma unroll
            for (int k = 0; k < 8; ++k) acc[b][uu][k] = 0.f;

    for (int e0 = 0; e0 < DOUT; e0 += EC) {
        for (int j = t; j < NBASIS * UT * EC; j += 256) {
            int b = j / (UT * EC);
            int rem = j % (UT * EC);
            int uu = rem / EC, c = rem % EC;
            int u = ub + uu;
            As[b][uu][c] = (u < NUSER) ? T[(b * NUSER + u) * DOUT + e0 + c] : 0.f;
        }
        for (int j = t; j < IT * EC; j += 256) {
            int ii = j / EC, c = j % EC;
            int i = ib + ii;
            Is[ii][c] = (i < NITEM) ? uv[(size_t)(NUSER + i) * DOUT + e0 + c] : 0.f;
        }
        __syncthreads();
        for (int c = 0; c < EC; ++c) {
            float av[NBASIS][2];
#pragma unroll
            for (int b = 0; b < NBASIS; ++b) {
                av[b][0] = As[b][tu][c];
                av[b][1] = As[b][tu + 16][c];
            }
            float iv[8];
#pragma unroll
            for (int k = 0; k < 8; ++k) iv[k] = Is[ti + 16 * k][c];
#pragma unroll
            for (int b = 0; b < NBASIS; ++b)
#pragma unroll
                for (int uu = 0; uu < 2; ++uu)
#pragma unroll
                    for (int k = 0; k < 8; ++k)
                        acc[b][uu][k] += av[b][uu] * iv[k];
        }
        __syncthreads();
    }

    float cf[NREL][NBASIS];
#pragma unroll
    for (int r = 0; r < NREL; ++r)
#pragma unroll
        for (int b = 0; b < NBASIS; ++b) cf[r][b] = coefs[r * NBASIS + b];

#pragma unroll
    for (int uu = 0; uu < 2; ++uu) {
        int u = ub + tu + uu * 16;
        if (u >= NUSER) continue;
#pragma unroll
        for (int k = 0; k < 8; ++k) {
            int i = ib + ti + 16 * k;
            if (i >= NITEM) continue;
            size_t base = ((size_t)u * NITEM + i) * NREL;
            float s0 = acc[0][uu][k], s1 = acc[1][uu][k];
#pragma unroll
            for (int r = 0; r < NREL; ++r)
                out[base + r] = cf[r][0] * s0 + cf[r][1] * s1;
        }
    }
}

// ---------------- launch -----------------------------------------------------
extern "C" void kernel_launch(void* const* d_in, const int* in_sizes, int n_in,
                              void* d_out, int out_size, void* d_ws, size_t ws_size,
                              hipStream_t stream) {
    const int*   x     = (const int*)d_in[0];
    const int*   ei    = (const int*)d_in[1];
    const int*   etype = (const int*)d_in[2];
    const float* enorm = (const float*)d_in[3];
    const float* basis = (const float*)d_in[4];
    const float* Wd    = (const float*)d_in[5];
    const float* bm    = (const float*)d_in[6];
    const float* coefs = (const float*)d_in[7];
    float* out = (float*)d_out;

    float* weight   = (float*)d_ws;                 // 7,500,000
    float* feat     = weight + 7500000;             // 1,500,000
    float* uv       = feat + 1500000;               // 225,000
    float* T        = uv + 225000;                  // 150,000
    float* csr_norm = T + 150000;                   // 200,000
    int*   csr_row  = (int*)(csr_norm + 200000);    // 200,000
    int*   deg      = csr_row + 200000;             // 3,000
    int*   offs     = deg + 3000;                   // 3,001
    int*   cursor   = offs + 3001;                  // 3,000

    const int* src = ei;
    const int* dst = ei + NEDGES;

    hipMemsetAsync(deg, 0, NNODES * sizeof(int), stream);
    k_cumsum<<<(NH / 4 + 255) / 256, 256, 0, stream>>>((const float4*)basis, (float4*)weight);
    k_degree<<<(NEDGES + 255) / 256, 256, 0, stream>>>(dst, deg);
    k_scan<<<1, 1024, 0, stream>>>(deg, offs, cursor);
    k_fill<<<(NEDGES + 255) / 256, 256, 0, stream>>>(src, dst, etype, enorm, x, cursor,
                                                     csr_row, csr_norm);
    k_agg<<<NNODES, 256, 0, stream>>>(weight, offs, csr_row, csr_norm, feat);
    k_dense<<<(NNODES + DN - 1) / DN, 128, 0, stream>>>(feat, Wd, uv);
    k_T<<<(NBASIS * NUSER * DOUT + 255) / 256, 256, 0, stream>>>(uv, bm, T);
    k_dec<<<dim3((NITEM + IT - 1) / IT, (NUSER + UT - 1) / UT), 256, 0, stream>>>(T, uv, coefs, out);
}

// Round 3
// 273.439 us; speedup vs baseline: 1.0496x; 1.0496x over previous
//
#include <hip/hip_runtime.h>
#include <hip/hip_bf16.h>

#define NUSER 1000
#define NNODES 3000
#define NREL 5
#define HID 500
#define DOUT 75
#define NBASIS 2
#define NEDGES 200000
#define NITEM (NNODES - NUSER)   // 2000
#define NH (NNODES * HID)        // 1,500,000

// ---- 1. weight = cumsum(ord_basis, axis=0), float4; also zeroes deg ---------
__global__ void k_cumsum(const float4* __restrict__ basis, float4* __restrict__ weight,
                         int* __restrict__ deg) {
    int i = blockIdx.x * blockDim.x + threadIdx.x;   // over NH/4 = 375000
    if (i < NNODES) deg[i] = 0;
    if (i >= NH / 4) return;
    float4 s = make_float4(0.f, 0.f, 0.f, 0.f);
#pragma unroll
    for (int r = 0; r < NREL; ++r) {
        float4 b = basis[r * (NH / 4) + i];
        s.x += b.x; s.y += b.y; s.z += b.z; s.w += b.w;
        weight[r * (NH / 4) + i] = s;
    }
}

// ---- 2. CSR build: degree, scan, fill ---------------------------------------
__global__ void k_degree(const int* __restrict__ dst, int* __restrict__ deg) {
    int e = blockIdx.x * blockDim.x + threadIdx.x;
    if (e < NEDGES) atomicAdd(&deg[dst[e]], 1);
}

__global__ __launch_bounds__(1024) void k_scan(const int* __restrict__ deg,
                                               int* __restrict__ offs,
                                               int* __restrict__ cursor) {
    __shared__ int wsum[16];
    int t = threadIdx.x;
    int base = t * 3;
    int a = (base     < NNODES) ? deg[base]     : 0;
    int b = (base + 1 < NNODES) ? deg[base + 1] : 0;
    int c = (base + 2 < NNODES) ? deg[base + 2] : 0;
    int s = a + b + c;
    int lane = t & 63, wid = t >> 6;
    // wave-level inclusive scan (no barriers)
    int v = s;
#pragma unroll
    for (int d = 1; d < 64; d <<= 1) {
        int x = __shfl_up(v, d);
        if (lane >= d) v += x;
    }
    if (lane == 63) wsum[wid] = v;
    __syncthreads();
    if (t < 16) {
        int w = wsum[t];
#pragma unroll
        for (int d = 1; d < 16; d <<= 1) {
            int x = __shfl_up(w, d);
            if (t >= d) w += x;
        }
        wsum[t] = w;          // inclusive wave-prefix
    }
    __syncthreads();
    int woff = wid ? wsum[wid - 1] : 0;
    int incl = v + woff;
    int excl = incl - s;
    if (base < NNODES)     { offs[base]     = excl;         cursor[base]     = excl; }
    if (base + 1 < NNODES) { offs[base + 1] = excl + a;     cursor[base + 1] = excl + a; }
    if (base + 2 < NNODES) { offs[base + 2] = excl + a + b; cursor[base + 2] = excl + a + b; }
    if (t == 1023) offs[NNODES] = incl;   // total = NEDGES
}

__global__ void k_fill(const int* __restrict__ src, const int* __restrict__ dst,
                       const int* __restrict__ etype, const float* __restrict__ enorm,
                       const int* __restrict__ x,
                       int* __restrict__ cursor, int* __restrict__ csr_row,
                       float* __restrict__ csr_norm) {
    int e = blockIdx.x * blockDim.x + threadIdx.x;
    if (e >= NEDGES) return;
    int d = dst[e];
    int pos = atomicAdd(&cursor[d], 1);
    csr_row[pos] = etype[e] * NNODES + x[src[e]];
    csr_norm[pos] = enorm[e];
}

// ---- 3. aggregation + relu: feat[n,:] = relu(sum_e norm * weight[row_e,:]) --
// float4 gather, 2 edges in flight (two 125-lane groups), LDS combine
__global__ __launch_bounds__(256) void k_agg(const float4* __restrict__ w4,
                                             const int* __restrict__ offs,
                                             const int* __restrict__ csr_row,
                                             const float* __restrict__ csr_norm,
                                             float4* __restrict__ feat4) {
    __shared__ float4 part[125];
    int n = blockIdx.x;
    int t = threadIdx.x;
    int beg = offs[n], end = offs[n + 1];
    int half = t >> 7;           // 0 or 1
    int lane = t & 127;          // 0..127, active <125
    float4 acc = make_float4(0.f, 0.f, 0.f, 0.f);
    if (lane < 125) {
        for (int p = beg + half; p < end; p += 2) {
            int row = csr_row[p];        // group-uniform, L2-sequential
            float w = csr_norm[p];
            float4 v = w4[(size_t)row * 125 + lane];
            acc.x += v.x * w; acc.y += v.y * w; acc.z += v.z * w; acc.w += v.w * w;
        }
    }
    if (half == 1 && lane < 125) part[lane] = acc;
    __syncthreads();
    if (half == 0 && lane < 125) {
        float4 o = part[lane];
        acc.x = fmaxf(acc.x + o.x, 0.f);
        acc.y = fmaxf(acc.y + o.y, 0.f);
        acc.z = fmaxf(acc.z + o.z, 0.f);
        acc.w = fmaxf(acc.w + o.w, 0.f);
        feat4[(size_t)n * 125 + lane] = acc;
    }
}

// ---- 4. dense: uv = relu(feat @ W), 8 nodes/block, 3 groups x 75 outputs ----
#define DN 8
__global__ __launch_bounds__(256) void k_dense(const float* __restrict__ feat,
                                               const float* __restrict__ W,
                                               float* __restrict__ uv) {
    __shared__ float lds[DN][HID];
    int nb = blockIdx.x * DN;            // 3000 % 8 == 0, always full tile
    int t = threadIdx.x;
    const float4* f4 = (const float4*)(feat + (size_t)nb * HID);
    float4* l4 = (float4*)&lds[0][0];
    for (int j = t; j < DN * HID / 4; j += 256) l4[j] = f4[j];
    __syncthreads();
    if (t < 225) {
        int g = t / 75, o = t % 75;      // group g owns nodes g, g+3, g+6
        float a0 = 0.f, a1 = 0.f, a2 = 0.f;
        for (int d = 0; d < HID; ++d) {
            float w = W[d * DOUT + o];   // coalesced 75-wide, L2-hot (150KB)
            a0 += lds[g][d] * w;
            a1 += lds[g + 3][d] * w;
            a2 += lds[(g + 6) & 7][d] * w;   // g=2 reads dummy row, discarded
        }
        uv[(nb + g) * DOUT + o]     = fmaxf(a0, 0.f);
        uv[(nb + g + 3) * DOUT + o] = fmaxf(a1, 0.f);
        if (g < 2) uv[(nb + g + 6) * DOUT + o] = fmaxf(a2, 0.f);
    }
}

// ---- 5. T[b,u,e] = sum_d uv[u,d] * bm[b,d,e]  (users only) ------------------
__global__ void k_T(const float* __restrict__ uv, const float* __restrict__ bm,
                    float* __restrict__ T) {
    int i = blockIdx.x * blockDim.x + threadIdx.x;   // over 2*1000*75
    if (i >= NBASIS * NUSER * DOUT) return;
    int b = i / (NUSER * DOUT);
    int rem = i % (NUSER * DOUT);
    int u = rem / DOUT;
    int e = rem % DOUT;
    float acc = 0.f;
    for (int d = 0; d < DOUT; ++d)
        acc += uv[u * DOUT + d] * bm[b * DOUT * DOUT + d * DOUT + e];
    T[i] = acc;
}

// ---- 6. decoder: out[u,i,r] = sum_b coefs[r,b] * T_b[u,:].item[i,:] ---------
// tile 32u x 128i; threads: 32 i-slots x 8 u-slots; per thread 2b x 4u x 4i
#define UT 32
#define IT 128
#define EC 25
__global__ __launch_bounds__(256) void k_dec(const float* __restrict__ T,
                                             const float* __restrict__ uv,
                                             const float* __restrict__ coefs,
                                             float* __restrict__ out) {
    __shared__ float As[NBASIS][UT][EC];
    __shared__ float Is[IT][EC];
    int t = threadIdx.x;
    int ti = t & 31;        // i-slot
    int tu = t >> 5;        // u-slot 0..7
    int ub = blockIdx.y * UT;
    int ib = blockIdx.x * IT;

    float acc[NBASIS][4][4] = {};

    for (int e0 = 0; e0 < DOUT; e0 += EC) {
        for (int j = t; j < NBASIS * UT * EC; j += 256) {
            int b = j / (UT * EC);
            int rem = j % (UT * EC);
            int uu = rem / EC, c = rem % EC;
            int u = ub + uu;
            As[b][uu][c] = (u < NUSER) ? T[(b * NUSER + u) * DOUT + e0 + c] : 0.f;
        }
        for (int j = t; j < IT * EC; j += 256) {
            int ii = j / EC, c = j % EC;
            int i = ib + ii;
            Is[ii][c] = (i < NITEM) ? uv[(size_t)(NUSER + i) * DOUT + e0 + c] : 0.f;
        }
        __syncthreads();
        for (int c = 0; c < EC; ++c) {
            float av[NBASIS][4];
#pragma unroll
            for (int b = 0; b < NBASIS; ++b)
#pragma unroll
                for (int uu = 0; uu < 4; ++uu)
                    av[b][uu] = As[b][tu * 4 + uu][c];
            float iv[4];
#pragma unroll
            for (int k = 0; k < 4; ++k) iv[k] = Is[ti + 32 * k][c];
#pragma unroll
            for (int b = 0; b < NBASIS; ++b)
#pragma unroll
                for (int uu = 0; uu < 4; ++uu)
#pragma unroll
                    for (int k = 0; k < 4; ++k)
                        acc[b][uu][k] += av[b][uu] * iv[k];
        }
        __syncthreads();
    }

    float cf[NREL][NBASIS];
#pragma unroll
    for (int r = 0; r < NREL; ++r)
#pragma unroll
        for (int b = 0; b < NBASIS; ++b) cf[r][b] = coefs[r * NBASIS + b];

#pragma unroll
    for (int uu = 0; uu < 4; ++uu) {
        int u = ub + tu * 4 + uu;
        if (u >= NUSER) continue;
#pragma unroll
        for (int k = 0; k < 4; ++k) {
            int i = ib + ti + 32 * k;
            if (i >= NITEM) continue;
            size_t base = ((size_t)u * NITEM + i) * NREL;
            float s0 = acc[0][uu][k], s1 = acc[1][uu][k];
#pragma unroll
            for (int r = 0; r < NREL; ++r)
                out[base + r] = cf[r][0] * s0 + cf[r][1] * s1;
        }
    }
}

// ---- launch -----------------------------------------------------------------
extern "C" void kernel_launch(void* const* d_in, const int* in_sizes, int n_in,
                              void* d_out, int out_size, void* d_ws, size_t ws_size,
                              hipStream_t stream) {
    const int*   x     = (const int*)d_in[0];
    const int*   ei    = (const int*)d_in[1];
    const int*   etype = (const int*)d_in[2];
    const float* enorm = (const float*)d_in[3];
    const float* basis = (const float*)d_in[4];
    const float* Wd    = (const float*)d_in[5];
    const float* bm    = (const float*)d_in[6];
    const float* coefs = (const float*)d_in[7];
    float* out = (float*)d_out;

    float* weight   = (float*)d_ws;                 // 7,500,000
    float* feat     = weight + 7500000;             // 1,500,000
    float* uv       = feat + 1500000;               // 225,000
    float* T        = uv + 225000;                  // 150,000
    float* csr_norm = T + 150000;                   // 200,000
    int*   csr_row  = (int*)(csr_norm + 200000);    // 200,000
    int*   deg      = csr_row + 200000;             // 3,000
    int*   offs     = deg + 3000;                   // 3,001
    int*   cursor   = offs + 3001;                  // 3,000

    const int* src = ei;
    const int* dst = ei + NEDGES;

    k_cumsum<<<(NH / 4 + 255) / 256, 256, 0, stream>>>((const float4*)basis,
                                                       (float4*)weight, deg);
    k_degree<<<(NEDGES + 255) / 256, 256, 0, stream>>>(dst, deg);
    k_scan<<<1, 1024, 0, stream>>>(deg, offs, cursor);
    k_fill<<<(NEDGES + 255) / 256, 256, 0, stream>>>(src, dst, etype, enorm, x, cursor,
                                                     csr_row, csr_norm);
    k_agg<<<NNODES, 256, 0, stream>>>((const float4*)weight, offs, csr_row, csr_norm,
                                      (float4*)feat);
    k_dense<<<NNODES / DN, 256, 0, stream>>>(feat, Wd, uv);
    k_T<<<(NBASIS * NUSER * DOUT + 255) / 256, 256, 0, stream>>>(uv, bm, T);
    k_dec<<<dim3((NITEM + IT - 1) / IT, (NUSER + UT - 1) / UT), 256, 0, stream>>>(T, uv, coefs, out);
}

// Round 6
// 262.655 us; speedup vs baseline: 1.0927x; 1.0411x over previous
//
#include <hip/hip_runtime.h>
#include <hip/hip_bf16.h>

#define NUSER 1000
#define NNODES 3000
#define NREL 5
#define HID 500
#define DOUT 75
#define NBASIS 2
#define NEDGES 200000
#define NITEM (NNODES - NUSER)   // 2000
#define NH (NNODES * HID)        // 1,500,000
#define ROWF4 125                // 500 floats = 125 float4 per row

// ---- 1. weight = cumsum(ord_basis, axis=0), float4; also zeroes deg ---------
__global__ void k_cumsum(const float4* __restrict__ basis, float4* __restrict__ weight,
                         int* __restrict__ deg) {
    int i = blockIdx.x * blockDim.x + threadIdx.x;   // over NH/4 = 375000
    if (i < NNODES) deg[i] = 0;
    if (i >= NH / 4) return;
    float4 s = make_float4(0.f, 0.f, 0.f, 0.f);
#pragma unroll
    for (int r = 0; r < NREL; ++r) {
        float4 b = basis[r * (NH / 4) + i];
        s.x += b.x; s.y += b.y; s.z += b.z; s.w += b.w;
        weight[r * (NH / 4) + i] = s;
    }
}

// ---- 2. CSR build: degree, scan, fill ---------------------------------------
__global__ void k_degree(const int* __restrict__ dst, int* __restrict__ deg) {
    int e = blockIdx.x * blockDim.x + threadIdx.x;
    if (e < NEDGES) atomicAdd(&deg[dst[e]], 1);
}

__global__ __launch_bounds__(1024) void k_scan(const int* __restrict__ deg,
                                               int* __restrict__ offs,
                                               int* __restrict__ cursor) {
    __shared__ int wsum[16];
    int t = threadIdx.x;
    int base = t * 3;
    int a = (base     < NNODES) ? deg[base]     : 0;
    int b = (base + 1 < NNODES) ? deg[base + 1] : 0;
    int c = (base + 2 < NNODES) ? deg[base + 2] : 0;
    int s = a + b + c;
    int lane = t & 63, wid = t >> 6;
    int v = s;
#pragma unroll
    for (int d = 1; d < 64; d <<= 1) {
        int x = __shfl_up(v, d);
        if (lane >= d) v += x;
    }
    if (lane == 63) wsum[wid] = v;
    __syncthreads();
    if (t < 16) {
        int w = wsum[t];
#pragma unroll
        for (int d = 1; d < 16; d <<= 1) {
            int x = __shfl_up(w, d);
            if (t >= d) w += x;
        }
        wsum[t] = w;
    }
    __syncthreads();
    int woff = wid ? wsum[wid - 1] : 0;
    int incl = v + woff;
    int excl = incl - s;
    if (base < NNODES)     { offs[base]     = excl;         cursor[base]     = excl; }
    if (base + 1 < NNODES) { offs[base + 1] = excl + a;     cursor[base + 1] = excl + a; }
    if (base + 2 < NNODES) { offs[base + 2] = excl + a + b; cursor[base + 2] = excl + a + b; }
    if (t == 1023) offs[NNODES] = incl;
}

__global__ void k_fill(const int* __restrict__ src, const int* __restrict__ dst,
                       const int* __restrict__ etype, const float* __restrict__ enorm,
                       const int* __restrict__ x,
                       int* __restrict__ cursor, int* __restrict__ csr_row,
                       float* __restrict__ csr_norm) {
    int e = blockIdx.x * blockDim.x + threadIdx.x;
    if (e >= NEDGES) return;
    int d = dst[e];
    int pos = atomicAdd(&cursor[d], 1);
    csr_row[pos] = etype[e] * NNODES + x[src[e]];
    csr_norm[pos] = enorm[e];
}

// ---- 3. aggregation + relu, column-sliced for per-XCD L2 residency ----------
// block b: node = b>>3, slice = b&7. Slices 0..6 = 16 float4 (64 floats),
// slice 7 = 13 float4 (52 floats). Working set per slice: 15000 rows x 256 B
// = 3.84 MB <= 4 MiB XCD L2 (slice->XCD pin via %8 round-robin dispatch).
// 256 threads = 16 edge-groups x 16 lanes; LDS tree-reduce across groups.
__global__ __launch_bounds__(256) void k_agg(const float4* __restrict__ w4,
                                             const int* __restrict__ offs,
                                             const int* __restrict__ csr_row,
                                             const float* __restrict__ csr_norm,
                                             float4* __restrict__ feat4) {
    __shared__ float4 part[16][16];
    int bid = blockIdx.x;
    int s = bid & 7;
    int n = bid >> 3;
    int t = threadIdx.x;
    int g = t >> 4;              // edge-group 0..15
    int lane = t & 15;
    int wdt = (s < 7) ? 16 : 13; // slice width in float4
    int boff = s * 16;           // float4 offset within row
    int beg = offs[n], end = offs[n + 1];
    float4 acc = make_float4(0.f, 0.f, 0.f, 0.f);
    if (lane < wdt) {
        for (int p = beg + g; p < end; p += 16) {
            int row = csr_row[p];      // 16-lane broadcast
            float wn = csr_norm[p];
            float4 v = w4[(size_t)row * ROWF4 + boff + lane];
            acc.x += v.x * wn; acc.y += v.y * wn; acc.z += v.z * wn; acc.w += v.w * wn;
        }
    }
    part[g][lane] = acc;
    __syncthreads();
#pragma unroll
    for (int st = 8; st >= 1; st >>= 1) {
        if (g < st) {
            float4 o = part[g + st][lane];
            float4 m = part[g][lane];
            m.x += o.x; m.y += o.y; m.z += o.z; m.w += o.w;
            part[g][lane] = m;
        }
        __syncthreads();
    }
    if (g == 0 && lane < wdt) {
        float4 m = part[0][lane];
        m.x = fmaxf(m.x, 0.f); m.y = fmaxf(m.y, 0.f);
        m.z = fmaxf(m.z, 0.f); m.w = fmaxf(m.w, 0.f);
        feat4[(size_t)n * ROWF4 + boff + lane] = m;
    }
}

// ---- 4. dense: uv = relu(feat @ W), 8 nodes/block, 3 groups x 75 outputs ----
#define DN 8
__global__ __launch_bounds__(256) void k_dense(const float* __restrict__ feat,
                                               const float* __restrict__ W,
                                               float* __restrict__ uv) {
    __shared__ float lds[DN][HID];
    int nb = blockIdx.x * DN;
    int t = threadIdx.x;
    const float4* f4 = (const float4*)(feat + (size_t)nb * HID);
    float4* l4 = (float4*)&lds[0][0];
    for (int j = t; j < DN * HID / 4; j += 256) l4[j] = f4[j];
    __syncthreads();
    if (t < 225) {
        int g = t / 75, o = t % 75;
        float a0 = 0.f, a1 = 0.f, a2 = 0.f;
        for (int d = 0; d < HID; ++d) {
            float w = W[d * DOUT + o];
            a0 += lds[g][d] * w;
            a1 += lds[g + 3][d] * w;
            a2 += lds[(g + 6) & 7][d] * w;
        }
        uv[(nb + g) * DOUT + o]     = fmaxf(a0, 0.f);
        uv[(nb + g + 3) * DOUT + o] = fmaxf(a1, 0.f);
        if (g < 2) uv[(nb + g + 6) * DOUT + o] = fmaxf(a2, 0.f);
    }
}

// ---- 5. T[b,u,e] = sum_d uv[u,d] * bm[b,d,e]  (users only) ------------------
__global__ void k_T(const float* __restrict__ uv, const float* __restrict__ bm,
                    float* __restrict__ T) {
    int i = blockIdx.x * blockDim.x + threadIdx.x;
    if (i >= NBASIS * NUSER * DOUT) return;
    int b = i / (NUSER * DOUT);
    int rem = i % (NUSER * DOUT);
    int u = rem / DOUT;
    int e = rem % DOUT;
    float acc = 0.f;
    for (int d = 0; d < DOUT; ++d)
        acc += uv[u * DOUT + d] * bm[b * DOUT * DOUT + d * DOUT + e];
    T[i] = acc;
}

// ---- 6. decoder -------------------------------------------------------------
#define UT 32
#define IT 128
#define EC 25
__global__ __launch_bounds__(256) void k_dec(const float* __restrict__ T,
                                             const float* __restrict__ uv,
                                             const float* __restrict__ coefs,
                                             float* __restrict__ out) {
    __shared__ float As[NBASIS][UT][EC];
    __shared__ float Is[IT][EC];
    int t = threadIdx.x;
    int ti = t & 31;
    int tu = t >> 5;
    int ub = blockIdx.y * UT;
    int ib = blockIdx.x * IT;

    float acc[NBASIS][4][4] = {};

    for (int e0 = 0; e0 < DOUT; e0 += EC) {
        for (int j = t; j < NBASIS * UT * EC; j += 256) {
            int b = j / (UT * EC);
            int rem = j % (UT * EC);
            int uu = rem / EC, c = rem % EC;
            int u = ub + uu;
            As[b][uu][c] = (u < NUSER) ? T[(b * NUSER + u) * DOUT + e0 + c] : 0.f;
        }
        for (int j = t; j < IT * EC; j += 256) {
            int ii = j / EC, c = j % EC;
            int i = ib + ii;
            Is[ii][c] = (i < NITEM) ? uv[(size_t)(NUSER + i) * DOUT + e0 + c] : 0.f;
        }
        __syncthreads();
        for (int c = 0; c < EC; ++c) {
            float av[NBASIS][4];
#pragma unroll
            for (int b = 0; b < NBASIS; ++b)
#pragma unroll
                for (int uu = 0; uu < 4; ++uu)
                    av[b][uu] = As[b][tu * 4 + uu][c];
            float iv[4];
#pragma unroll
            for (int k = 0; k < 4; ++k) iv[k] = Is[ti + 32 * k][c];
#pragma unroll
            for (int b = 0; b < NBASIS; ++b)
#pragma unroll
                for (int uu = 0; uu < 4; ++uu)
#pragma unroll
                    for (int k = 0; k < 4; ++k)
                        acc[b][uu][k] += av[b][uu] * iv[k];
        }
        __syncthreads();
    }

    float cf[NREL][NBASIS];
#pragma unroll
    for (int r = 0; r < NREL; ++r)
#pragma unroll
        for (int b = 0; b < NBASIS; ++b) cf[r][b] = coefs[r * NBASIS + b];

#pragma unroll
    for (int uu = 0; uu < 4; ++uu) {
        int u = ub + tu * 4 + uu;
        if (u >= NUSER) continue;
#pragma unroll
        for (int k = 0; k < 4; ++k) {
            int i = ib + ti + 32 * k;
            if (i >= NITEM) continue;
            size_t base = ((size_t)u * NITEM + i) * NREL;
            float s0 = acc[0][uu][k], s1 = acc[1][uu][k];
#pragma unroll
            for (int r = 0; r < NREL; ++r)
                out[base + r] = cf[r][0] * s0 + cf[r][1] * s1;
        }
    }
}

// ---- launch -----------------------------------------------------------------
extern "C" void kernel_launch(void* const* d_in, const int* in_sizes, int n_in,
                              void* d_out, int out_size, void* d_ws, size_t ws_size,
                              hipStream_t stream) {
    const int*   x     = (const int*)d_in[0];
    const int*   ei    = (const int*)d_in[1];
    const int*   etype = (const int*)d_in[2];
    const float* enorm = (const float*)d_in[3];
    const float* basis = (const float*)d_in[4];
    const float* Wd    = (const float*)d_in[5];
    const float* bm    = (const float*)d_in[6];
    const float* coefs = (const float*)d_in[7];
    float* out = (float*)d_out;

    float* weight   = (float*)d_ws;                 // 7,500,000
    float* feat     = weight + 7500000;             // 1,500,000
    float* uv       = feat + 1500000;               // 225,000
    float* T        = uv + 225000;                  // 150,000
    float* csr_norm = T + 150000;                   // 200,000
    int*   csr_row  = (int*)(csr_norm + 200000);    // 200,000
    int*   deg      = csr_row + 200000;             // 3,000
    int*   offs     = deg + 3000;                   // 3,001
    int*   cursor   = offs + 3001;                  // 3,000

    const int* src = ei;
    const int* dst = ei + NEDGES;

    k_cumsum<<<(NH / 4 + 255) / 256, 256, 0, stream>>>((const float4*)basis,
                                                       (float4*)weight, deg);
    k_degree<<<(NEDGES + 255) / 256, 256, 0, stream>>>(dst, deg);
    k_scan<<<1, 1024, 0, stream>>>(deg, offs, cursor);
    k_fill<<<(NEDGES + 255) / 256, 256, 0, stream>>>(src, dst, etype, enorm, x, cursor,
                                                     csr_row, csr_norm);
    k_agg<<<NNODES * 8, 256, 0, stream>>>((const float4*)weight, offs, csr_row, csr_norm,
                                          (float4*)feat);
    k_dense<<<NNODES / DN, 256, 0, stream>>>(feat, Wd, uv);
    k_T<<<(NBASIS * NUSER * DOUT + 255) / 256, 256, 0, stream>>>(uv, bm, T);
    k_dec<<<dim3((NITEM + IT - 1) / IT, (NUSER + UT - 1) / UT), 256, 0, stream>>>(T, uv, coefs, out);
}